// Round 4
// baseline (2907.579 us; speedup 1.0000x reference)
//
#include <hip/hip_runtime.h>
#include <stdint.h>

#define D_IN 250
#define H_DIM 100
#define BM 64             // rows per block (4 waves x 16 rows)
#define NTHREADS 256

#define CHUNK_E (21*512)  // 10752 bf16 elems per 21-tile K-chunk
#define NCH 28            // 0..7 P1X, 8..11 P1H, 12..19 P2X, 20..23 P2P, 24..27 P2S
#define TOTAL_E (NCH*CHUNK_E)

typedef __bf16 bf16x8 __attribute__((ext_vector_type(8)));
typedef float f32x4 __attribute__((ext_vector_type(4)));

static __device__ __forceinline__ uint16_t f2bf(float f) {
  uint32_t u = __builtin_bit_cast(uint32_t, f);
  u = (u + 0x7FFFu + ((u >> 16) & 1u)) >> 16;
  return (uint16_t)u;
}
static __device__ __forceinline__ float bf2f(uint16_t h) {
  uint32_t u = ((uint32_t)h) << 16;
  return __builtin_bit_cast(float, u);
}
static __device__ __forceinline__ float sigmoidf_(float x) {
  return 1.0f / (1.0f + __expf(-x));
}
static __device__ __forceinline__ float tanhf_(float x) {
  return 2.0f / (1.0f + __expf(-2.0f * x)) - 1.0f;
}

// ---------------- weight prepack: fp32 -> bf16 B-fragment layout -------------
// per chunk: [nt(21)][lane(64)][j(8)]; k_loc=(lane>>4)*8+j, npad=nt*16+(lane&15)
// Biases folded in: P1X row k=250 = bi; P1H row k=100 = bh.
__global__ void prepack_kernel(const float* __restrict__ Wi, const float* __restrict__ Wh,
                               const float* __restrict__ W_z, const float* __restrict__ U_z,
                               const float* __restrict__ Us_z, const float* __restrict__ W_r,
                               const float* __restrict__ U_r, const float* __restrict__ Us_r,
                               const float* __restrict__ W_hn, const float* __restrict__ U_hn,
                               const float* __restrict__ Us_hn, const float* __restrict__ bi,
                               const float* __restrict__ bh, uint16_t* __restrict__ ws) {
  int idx = blockIdx.x * blockDim.x + threadIdx.x;
  if (idx >= TOTAL_E) return;
  int chunk = idx / CHUNK_E;
  int a = idx % CHUNK_E;
  int j = a & 7, lane = (a >> 3) & 63, nt = a >> 9;
  int kloc = ((lane >> 4) << 3) + j;
  int npad = nt * 16 + (lane & 15);
  int g = npad / 112, c = npad % 112;
  float val = 0.f;
  if (chunk < 8) {            // pass1 X-section: Wi (r,z,n) + bias bi at k=250
    int k = chunk * 32 + kloc;
    if (c < H_DIM) {
      if (k < D_IN)       val = Wi[(size_t)(g * H_DIM + c) * D_IN + k];
      else if (k == D_IN) val = bi[g * H_DIM + c];
    }
  } else if (chunk < 12) {    // pass1 Hs-section: Wh (r,z,n) + bias bh at k=100
    int k = (chunk - 8) * 32 + kloc;
    if (c < H_DIM) {
      if (k < H_DIM)       val = Wh[(size_t)(g * H_DIM + c) * H_DIM + k];
      else if (k == H_DIM) val = bh[g * H_DIM + c];
    }
  } else if (chunk < 20) {    // pass2 X-section: W_z, W_r, W_hn (z,r,hn)
    int k = (chunk - 12) * 32 + kloc;
    if (c < H_DIM && k < D_IN) {
      const float* W = g == 0 ? W_z : g == 1 ? W_r : W_hn;
      val = W[(size_t)c * D_IN + k];
    }
  } else if (chunk < 24) {    // pass2 Hp-section: U_z, U_r, U_hn
    int k = (chunk - 20) * 32 + kloc;
    if (c < H_DIM && k < H_DIM) {
      const float* W = g == 0 ? U_z : g == 1 ? U_r : U_hn;
      val = W[(size_t)c * H_DIM + k];
    }
  } else {                    // pass2 HsNew-section: Us_z, Us_r, Us_hn
    int k = (chunk - 24) * 32 + kloc;
    if (c < H_DIM && k < H_DIM) {
      const float* W = g == 0 ? Us_z : g == 1 ? Us_r : Us_hn;
      val = W[(size_t)c * H_DIM + k];
    }
  }
  ws[idx] = f2bf(val);
}

// ------------------------- A-fragment direct loaders -------------------------
// lane holds A[row=lane&15][k = (lane>>4)*8 + j]; xr points at this lane's row.
static __device__ __forceinline__ bf16x8 xfrag(const float* __restrict__ xr, int ks, int q) {
  int c0 = ks * 32 + q * 8;
  bf16x8 a;
  if (c0 < 248) {
    #pragma unroll
    for (int i = 0; i < 4; ++i) {
      float2 f = *(const float2*)(xr + c0 + 2 * i);
      a[2 * i] = (__bf16)f.x; a[2 * i + 1] = (__bf16)f.y;
    }
  } else {                    // cols 248,249 valid; 250 = bias 1.0; rest 0
    float2 f = *(const float2*)(xr + 248);
    a[0] = (__bf16)f.x; a[1] = (__bf16)f.y; a[2] = (__bf16)1.0f;
    #pragma unroll
    for (int i = 3; i < 8; ++i) a[i] = (__bf16)0.0f;
  }
  return a;
}

static __device__ __forceinline__ bf16x8 hfrag(const float* __restrict__ hr, int ks, int q, float bias) {
  int c0 = ks * 32 + q * 8;   // 0..120
  bf16x8 a;
  #pragma unroll
  for (int i = 0; i < 8; ++i) a[i] = (__bf16)0.0f;
  if (c0 <= 88) {
    #pragma unroll
    for (int i = 0; i < 4; ++i) {
      float2 f = *(const float2*)(hr + c0 + 2 * i);
      a[2 * i] = (__bf16)f.x; a[2 * i + 1] = (__bf16)f.y;
    }
  } else if (c0 == 96) {      // cols 96..99 valid; 100 = bias; rest 0
    float2 f0 = *(const float2*)(hr + 96);
    float2 f1 = *(const float2*)(hr + 98);
    a[0] = (__bf16)f0.x; a[1] = (__bf16)f0.y; a[2] = (__bf16)f1.x; a[3] = (__bf16)f1.y;
    a[4] = (__bf16)bias;
  }
  return a;
}

// ------------------------------ MFMA helpers ---------------------------------
static __device__ __forceinline__ void full21(bf16x8 a, const uint16_t* __restrict__ bp,
                                              f32x4* __restrict__ accA) {
  #pragma unroll
  for (int nt = 0; nt < 21; ++nt) {
    bf16x8 b = *(const bf16x8*)(bp + nt * 512);
    accA[nt] = __builtin_amdgcn_mfma_f32_16x16x32_bf16(a, b, accA[nt], 0, 0, 0);
  }
}
static __device__ __forceinline__ void split21(bf16x8 a, const uint16_t* __restrict__ bp,
                                               f32x4* __restrict__ accA, f32x4* __restrict__ accB) {
  #pragma unroll
  for (int nt = 0; nt < 14; ++nt) {
    bf16x8 b = *(const bf16x8*)(bp + nt * 512);
    accA[nt] = __builtin_amdgcn_mfma_f32_16x16x32_bf16(a, b, accA[nt], 0, 0, 0);
  }
  #pragma unroll
  for (int nt = 14; nt < 21; ++nt) {
    bf16x8 b = *(const bf16x8*)(bp + nt * 512);
    accB[nt - 14] = __builtin_amdgcn_mfma_f32_16x16x32_bf16(a, b, accB[nt - 14], 0, 0, 0);
  }
}

// ---------------------------- fused GRU kernel -------------------------------
// Fully wave-independent, ZERO barriers. LDS = HsNew only (16KB).
__global__ __launch_bounds__(NTHREADS, 8) void gru_fused(
    const float* __restrict__ x, const float* __restrict__ hp_g,
    const float* __restrict__ hs_g, const uint16_t* __restrict__ ws,
    float* __restrict__ out) {
  __shared__ __align__(16) uint16_t ldsHsN[BM * 128];   // 16384 B

  const int tid = threadIdx.x;
  const int lane = tid & 63, wid = tid >> 6;
  const int q = lane >> 4, cl = lane & 15;
  const int rowbase = blockIdx.x * BM;
  const int wrow0 = wid * 16;

  const float* xr  = x    + (size_t)(rowbase + wrow0 + cl) * D_IN;
  const float* hsr = hs_g + (size_t)(rowbase + wrow0 + cl) * H_DIM;
  const float* hpr = hp_g + (size_t)(rowbase + wrow0 + cl) * H_DIM;
  const uint16_t* wsl = ws + lane * 8;

  f32x4 accA[21], accB[7];

  // =========================== PASS 1 (GRU cell) ============================
  #pragma unroll
  for (int i = 0; i < 21; ++i) accA[i] = (f32x4)(0.f);
  #pragma unroll
  for (int i = 0; i < 7; ++i) accB[i] = (f32x4)(0.f);

  #pragma unroll 1
  for (int ks = 0; ks < 8; ++ks) {        // X @ Wi (+bias via col 250)
    bf16x8 a = xfrag(xr, ks, q);
    full21(a, wsl + (size_t)ks * CHUNK_E, accA);
  }
  #pragma unroll 1
  for (int ks = 0; ks < 4; ++ks) {        // Hs @ Wh (+bias via col 100); n-tiles -> accB
    bf16x8 a = hfrag(hsr, ks, q, 1.0f);
    split21(a, wsl + (size_t)(8 + ks) * CHUNK_E, accA, accB);
  }

  // ---- stage3: elementwise GRU cell -> HsNew (bf16) into LDS ----
  {
    const float* hse = hs_g + (size_t)(rowbase + wrow0 + q * 4) * H_DIM;
    #pragma unroll
    for (int t = 0; t < 7; ++t) {
      int c = t * 16 + cl;
      bool valid = c < H_DIM;
      #pragma unroll
      for (int r = 0; r < 4; ++r) {
        int rl = wrow0 + q * 4 + r;
        float rr = sigmoidf_(accA[t][r]);
        float zz = sigmoidf_(accA[7 + t][r]);
        float nn = tanhf_(accA[14 + t][r] + rr * accB[t][r]);
        float hsp = valid ? hse[r * H_DIM + c] : 0.f;
        float hsn = (1.f - zz) * nn + zz * hsp;
        int hb = rl * 256 + ((c * 2) ^ ((rl & 7) << 4));
        *(uint16_t*)((char*)ldsHsN + hb) = f2bf(hsn);
      }
    }
    // zero pad cols 112..127 of this wave's 16 rows
    int prow = wrow0 + (lane >> 2);
    int pcol = 112 + (lane & 3) * 4;
    int pb = prow * 256 + ((pcol * 2) ^ ((prow & 7) << 4));
    ushort4 z4; z4.x = 0; z4.y = 0; z4.z = 0; z4.w = 0;
    *(ushort4*)((char*)ldsHsN + pb) = z4;
  }

  // =========================== PASS 2 (task head) ===========================
  #pragma unroll
  for (int i = 0; i < 21; ++i) accA[i] = (f32x4)(0.f);
  #pragma unroll
  for (int i = 0; i < 7; ++i) accB[i] = (f32x4)(0.f);

  #pragma unroll 1
  for (int ks = 0; ks < 8; ++ks) {        // X @ (W_z,W_r,W_hn)
    bf16x8 a = xfrag(xr, ks, q);
    full21(a, wsl + (size_t)(12 + ks) * CHUNK_E, accA);
  }
  #pragma unroll 1
  for (int ks = 0; ks < 4; ++ks) {        // Hp @ (U_z,U_r,U_hn); U_hn -> accB
    bf16x8 a = hfrag(hpr, ks, q, 0.0f);
    split21(a, wsl + (size_t)(20 + ks) * CHUNK_E, accA, accB);
  }
  {
    const int arow = wrow0 + cl;
    #pragma unroll 1
    for (int ks = 0; ks < 4; ++ks) {      // HsNew @ (Us_z,Us_r,Us_hn)
      int ab = arow * 256 + (((ks * 64) + q * 16) ^ ((arow & 7) << 4));
      bf16x8 a = *(const bf16x8*)((const char*)ldsHsN + ab);
      full21(a, wsl + (size_t)(24 + ks) * CHUNK_E, accA);
    }
  }

  // ---- stage5: task elementwise + store ----
  {
    const float* hpe = hp_g + (size_t)(rowbase + wrow0 + q * 4) * H_DIM;
    float* oute = out + (size_t)(rowbase + wrow0 + q * 4) * H_DIM;
    #pragma unroll
    for (int t = 0; t < 7; ++t) {
      int c = t * 16 + cl;
      bool valid = c < H_DIM;
      #pragma unroll
      for (int r = 0; r < 4; ++r) {
        float z2 = sigmoidf_(accA[t][r]);
        float r2 = sigmoidf_(accA[7 + t][r]);
        float nm = tanhf_(accA[14 + t][r] + r2 * accB[t][r]);
        float hpv = valid ? hpe[r * H_DIM + c] : 0.f;
        float hnew = (1.f - z2) * nm + z2 * hpv;
        if (valid) oute[r * H_DIM + c] = hnew;
      }
    }
  }
}

extern "C" void kernel_launch(void* const* d_in, const int* in_sizes, int n_in,
                              void* d_out, int out_size, void* d_ws, size_t ws_size,
                              hipStream_t stream) {
  const float* x    = (const float*)d_in[0];
  const float* h_p  = (const float*)d_in[1];
  const float* h_s  = (const float*)d_in[2];
  const float* Wi   = (const float*)d_in[3];
  const float* Wh   = (const float*)d_in[4];
  const float* bi   = (const float*)d_in[5];
  const float* bh   = (const float*)d_in[6];
  const float* W_z  = (const float*)d_in[7];
  const float* U_z  = (const float*)d_in[8];
  const float* Us_z = (const float*)d_in[9];
  const float* W_r  = (const float*)d_in[10];
  const float* U_r  = (const float*)d_in[11];
  const float* Us_r = (const float*)d_in[12];
  const float* W_hn = (const float*)d_in[13];
  const float* U_hn = (const float*)d_in[14];
  const float* Us_hn= (const float*)d_in[15];
  uint16_t* ws = (uint16_t*)d_ws;
  float* out = (float*)d_out;

  int rows = in_sizes[0] / D_IN;          // 262144
  prepack_kernel<<<(TOTAL_E + 255) / 256, 256, 0, stream>>>(
      Wi, Wh, W_z, U_z, Us_z, W_r, U_r, Us_r, W_hn, U_hn, Us_hn, bi, bh, ws);
  gru_fused<<<rows / BM, NTHREADS, 0, stream>>>(x, h_p, h_s, ws, out);
}

// Round 5
// 378.611 us; speedup vs baseline: 7.6796x; 7.6796x over previous
//
#include <hip/hip_runtime.h>
#include <stdint.h>

#define D_IN 250
#define H_DIM 100
#define RPW 32            // rows per wave
#define NTHREADS 256      // 4 waves
#define BM (4*RPW)        // 128 rows per block

// ws layout: 588 fragments of 512 bf16 elems each.
// pass1 frag id = t*36 + ks*3 + g      (t 0..6, ks 0..11 [0-7 X, 8-11 Hs], g 0..2 [r,z,n])
// pass2 frag id = 252 + t*48 + ks*3+g  (ks 0..15 [0-7 X, 8-11 Hp, 12-15 HsN], g [z,r,hn])
#define P2_FRAG 252
#define TOTAL_E ((252 + 336) * 512)     // 301056 elems

typedef __bf16 bf16x8 __attribute__((ext_vector_type(8)));
typedef float f32x4 __attribute__((ext_vector_type(4)));

static __device__ __forceinline__ uint16_t f2bf(float f) {
  uint32_t u = __builtin_bit_cast(uint32_t, f);
  u = (u + 0x7FFFu + ((u >> 16) & 1u)) >> 16;
  return (uint16_t)u;
}
static __device__ __forceinline__ float sigmoidf_(float x) {
  return 1.0f / (1.0f + __expf(-x));
}
static __device__ __forceinline__ float tanhf_(float x) {
  return 2.0f / (1.0f + __expf(-2.0f * x)) - 1.0f;
}

// ---------------- weight prepack: fp32 -> bf16 B-fragment layout -------------
// within a frag: [lane(64)][j(8)]; k_loc=(lane>>4)*8+j, col c = t*16+(lane&15)
// bias folded: pass1 X k==250 -> bi ; pass1 Hs k==100 -> bh ; pass2 -> 0
__global__ void prepack_kernel(const float* __restrict__ Wi, const float* __restrict__ Wh,
                               const float* __restrict__ W_z, const float* __restrict__ U_z,
                               const float* __restrict__ Us_z, const float* __restrict__ W_r,
                               const float* __restrict__ U_r, const float* __restrict__ Us_r,
                               const float* __restrict__ W_hn, const float* __restrict__ U_hn,
                               const float* __restrict__ Us_hn, const float* __restrict__ bi,
                               const float* __restrict__ bh, uint16_t* __restrict__ ws) {
  int idx = blockIdx.x * blockDim.x + threadIdx.x;
  if (idx >= TOTAL_E) return;
  int f = idx >> 9;
  int a = idx & 511;
  int lane = a >> 3, j = a & 7;
  int kloc = ((lane >> 4) << 3) + j;
  int cl = lane & 15;
  float val = 0.f;
  if (f < P2_FRAG) {
    int g = f % 3, ks = (f / 3) % 12, t = f / 36;
    int c = t * 16 + cl;
    if (c < H_DIM) {
      if (ks < 8) {
        int k = ks * 32 + kloc;
        if (k < D_IN)       val = Wi[(size_t)(g * H_DIM + c) * D_IN + k];
        else if (k == D_IN) val = bi[g * H_DIM + c];
      } else {
        int k = (ks - 8) * 32 + kloc;
        if (k < H_DIM)       val = Wh[(size_t)(g * H_DIM + c) * H_DIM + k];
        else if (k == H_DIM) val = bh[g * H_DIM + c];
      }
    }
  } else {
    int f2 = f - P2_FRAG;
    int g = f2 % 3, ks = (f2 / 3) % 16, t = f2 / 48;
    int c = t * 16 + cl;
    if (c < H_DIM) {
      if (ks < 8) {
        int k = ks * 32 + kloc;
        const float* W = g == 0 ? W_z : g == 1 ? W_r : W_hn;
        if (k < D_IN) val = W[(size_t)c * D_IN + k];
      } else if (ks < 12) {
        int k = (ks - 8) * 32 + kloc;
        const float* W = g == 0 ? U_z : g == 1 ? U_r : U_hn;
        if (k < H_DIM) val = W[(size_t)c * H_DIM + k];
      } else {
        int k = (ks - 12) * 32 + kloc;
        const float* W = g == 0 ? Us_z : g == 1 ? Us_r : Us_hn;
        if (k < H_DIM) val = W[(size_t)c * H_DIM + k];
      }
    }
  }
  ws[idx] = f2bf(val);
}

// ------------------------- A-fragment direct loaders -------------------------
static __device__ __forceinline__ bf16x8 xfrag(const float* __restrict__ xr, int ks, int q) {
  int c0 = ks * 32 + q * 8;
  bf16x8 a;
  if (c0 < 248) {
    #pragma unroll
    for (int i = 0; i < 4; ++i) {
      float2 f = *(const float2*)(xr + c0 + 2 * i);
      a[2 * i] = (__bf16)f.x; a[2 * i + 1] = (__bf16)f.y;
    }
  } else {                    // cols 248,249 valid; 250 = bias 1.0; rest 0
    float2 f = *(const float2*)(xr + 248);
    a[0] = (__bf16)f.x; a[1] = (__bf16)f.y; a[2] = (__bf16)1.0f;
    a[3] = (__bf16)0.0f; a[4] = (__bf16)0.0f; a[5] = (__bf16)0.0f;
    a[6] = (__bf16)0.0f; a[7] = (__bf16)0.0f;
  }
  return a;
}
static __device__ __forceinline__ bf16x8 hfrag(const float* __restrict__ hr, int ks, int q, float bias) {
  int c0 = ks * 32 + q * 8;
  bf16x8 a;
  #pragma unroll
  for (int i = 0; i < 8; ++i) a[i] = (__bf16)0.0f;
  if (c0 <= 88) {
    #pragma unroll
    for (int i = 0; i < 4; ++i) {
      float2 f = *(const float2*)(hr + c0 + 2 * i);
      a[2 * i] = (__bf16)f.x; a[2 * i + 1] = (__bf16)f.y;
    }
  } else if (c0 == 96) {      // cols 96..99 valid; 100 = bias; rest 0
    float2 f0 = *(const float2*)(hr + 96);
    float2 f1 = *(const float2*)(hr + 98);
    a[0] = (__bf16)f0.x; a[1] = (__bf16)f0.y; a[2] = (__bf16)f1.x; a[3] = (__bf16)f1.y;
    a[4] = (__bf16)bias;
  }
  return a;
}

#define MFMA(A, B, C) __builtin_amdgcn_mfma_f32_16x16x32_bf16((A), (B), (C), 0, 0, 0)

// ---------------------------- fused GRU kernel -------------------------------
// nt-outer / K-inner. A-operands cached in registers; only 4 accs live per tile.
// Wave-private LDS transpose slab for HsNew. ZERO barriers.
__global__ __launch_bounds__(NTHREADS, 2) void gru_fused(
    const float* __restrict__ x, const float* __restrict__ hp_g,
    const float* __restrict__ hs_g, const uint16_t* __restrict__ ws,
    float* __restrict__ out) {
  __shared__ __align__(16) uint16_t ldsT[4 * RPW * 128];   // 32 KB, wave-private slabs

  const int tid = threadIdx.x;
  const int lane = tid & 63, wid = tid >> 6;
  const int q = lane >> 4, cl = lane & 15;
  const int rowbase = blockIdx.x * BM + wid * RPW;   // this wave's first global row
  uint16_t* lT = ldsT + wid * RPW * 128;

  // zero pad-cols 112..127 of the transpose slab (read by pass2 ks=3 frags)
  {
    int r0 = lane >> 1;
    int col = 112 + (lane & 1) * 8;
    int bo = r0 * 256 + ((col * 2) ^ ((r0 & 7) << 4));
    uint4 z; z.x = 0; z.y = 0; z.z = 0; z.w = 0;
    *(uint4*)((char*)lT + bo) = z;
  }

  // ---- load & convert A fragments (held in registers across all tiles) ----
  bf16x8 xa[2][8], ha[2][4];
  #pragma unroll
  for (int h = 0; h < 2; ++h) {
    const float* xr = x + (size_t)(rowbase + h * 16 + cl) * D_IN;
    #pragma unroll
    for (int ks = 0; ks < 8; ++ks) xa[h][ks] = xfrag(xr, ks, q);
    const float* hr = hs_g + (size_t)(rowbase + h * 16 + cl) * H_DIM;
    #pragma unroll
    for (int ks = 0; ks < 4; ++ks) ha[h][ks] = hfrag(hr, ks, q, 1.0f);
  }

  const uint16_t* wsl = ws + lane * 8;

  // =========================== PASS 1 (GRU cell) ============================
  #pragma unroll 1
  for (int t = 0; t < 7; ++t) {
    f32x4 aR[2], aZ[2], aNi[2], aNh[2];
    #pragma unroll
    for (int h = 0; h < 2; ++h) { aR[h] = (f32x4)(0.f); aZ[h] = (f32x4)(0.f); aNi[h] = (f32x4)(0.f); aNh[h] = (f32x4)(0.f); }
    const uint16_t* bp = wsl + (size_t)t * (36 * 512);
    #pragma unroll
    for (int ks = 0; ks < 8; ++ks) {
      bf16x8 b0 = *(const bf16x8*)(bp + (ks * 3 + 0) * 512);
      bf16x8 b1 = *(const bf16x8*)(bp + (ks * 3 + 1) * 512);
      bf16x8 b2 = *(const bf16x8*)(bp + (ks * 3 + 2) * 512);
      #pragma unroll
      for (int h = 0; h < 2; ++h) {
        aR[h]  = MFMA(xa[h][ks], b0, aR[h]);
        aZ[h]  = MFMA(xa[h][ks], b1, aZ[h]);
        aNi[h] = MFMA(xa[h][ks], b2, aNi[h]);
      }
    }
    #pragma unroll
    for (int ks = 0; ks < 4; ++ks) {
      bf16x8 b0 = *(const bf16x8*)(bp + ((8 + ks) * 3 + 0) * 512);
      bf16x8 b1 = *(const bf16x8*)(bp + ((8 + ks) * 3 + 1) * 512);
      bf16x8 b2 = *(const bf16x8*)(bp + ((8 + ks) * 3 + 2) * 512);
      #pragma unroll
      for (int h = 0; h < 2; ++h) {
        aR[h]  = MFMA(ha[h][ks], b0, aR[h]);
        aZ[h]  = MFMA(ha[h][ks], b1, aZ[h]);
        aNh[h] = MFMA(ha[h][ks], b2, aNh[h]);
      }
    }
    // elementwise -> HsNew tile into LDS (cols >=100 compute exactly 0)
    int c = t * 16 + cl;
    bool valid = c < H_DIM;
    #pragma unroll
    for (int h = 0; h < 2; ++h) {
      #pragma unroll
      for (int r = 0; r < 4; ++r) {
        int row = h * 16 + q * 4 + r;
        float hsp = valid ? hs_g[(size_t)(rowbase + row) * H_DIM + c] : 0.f;
        float rr = sigmoidf_(aR[h][r]);
        float zz = sigmoidf_(aZ[h][r]);
        float nn = tanhf_(aNi[h][r] + rr * aNh[h][r]);
        float hsn = (1.f - zz) * nn + zz * hsp;
        int bo = row * 256 + ((c * 2) ^ ((row & 7) << 4));
        *(uint16_t*)((char*)lT + bo) = f2bf(hsn);
      }
    }
  }

  // ---- load Hp fragments; read HsNew fragments back (wave-private, no barrier) ----
  bf16x8 pa[2][4], na[2][4];
  #pragma unroll
  for (int h = 0; h < 2; ++h) {
    const float* pr = hp_g + (size_t)(rowbase + h * 16 + cl) * H_DIM;
    #pragma unroll
    for (int ks = 0; ks < 4; ++ks) pa[h][ks] = hfrag(pr, ks, q, 0.0f);
  }
  #pragma unroll
  for (int h = 0; h < 2; ++h) {
    int row = h * 16 + cl;
    #pragma unroll
    for (int ks = 0; ks < 4; ++ks) {
      int bo = row * 256 + (((ks * 64) + q * 16) ^ ((row & 7) << 4));
      na[h][ks] = *(const bf16x8*)((const char*)lT + bo);
    }
  }

  // =========================== PASS 2 (task head) ===========================
  #pragma unroll 1
  for (int t = 0; t < 7; ++t) {
    f32x4 aZ[2], aR[2], aNa[2], aNb[2];
    #pragma unroll
    for (int h = 0; h < 2; ++h) { aZ[h] = (f32x4)(0.f); aR[h] = (f32x4)(0.f); aNa[h] = (f32x4)(0.f); aNb[h] = (f32x4)(0.f); }
    const uint16_t* bp = wsl + (size_t)(P2_FRAG * 512) + (size_t)t * (48 * 512);
    #pragma unroll
    for (int ks = 0; ks < 8; ++ks) {
      bf16x8 b0 = *(const bf16x8*)(bp + (ks * 3 + 0) * 512);
      bf16x8 b1 = *(const bf16x8*)(bp + (ks * 3 + 1) * 512);
      bf16x8 b2 = *(const bf16x8*)(bp + (ks * 3 + 2) * 512);
      #pragma unroll
      for (int h = 0; h < 2; ++h) {
        aZ[h]  = MFMA(xa[h][ks], b0, aZ[h]);
        aR[h]  = MFMA(xa[h][ks], b1, aR[h]);
        aNa[h] = MFMA(xa[h][ks], b2, aNa[h]);
      }
    }
    #pragma unroll
    for (int ks = 0; ks < 4; ++ks) {
      bf16x8 b0 = *(const bf16x8*)(bp + ((8 + ks) * 3 + 0) * 512);
      bf16x8 b1 = *(const bf16x8*)(bp + ((8 + ks) * 3 + 1) * 512);
      bf16x8 b2 = *(const bf16x8*)(bp + ((8 + ks) * 3 + 2) * 512);
      #pragma unroll
      for (int h = 0; h < 2; ++h) {
        aZ[h]  = MFMA(pa[h][ks], b0, aZ[h]);
        aR[h]  = MFMA(pa[h][ks], b1, aR[h]);
        aNb[h] = MFMA(pa[h][ks], b2, aNb[h]);
      }
    }
    #pragma unroll
    for (int ks = 0; ks < 4; ++ks) {
      bf16x8 b0 = *(const bf16x8*)(bp + ((12 + ks) * 3 + 0) * 512);
      bf16x8 b1 = *(const bf16x8*)(bp + ((12 + ks) * 3 + 1) * 512);
      bf16x8 b2 = *(const bf16x8*)(bp + ((12 + ks) * 3 + 2) * 512);
      #pragma unroll
      for (int h = 0; h < 2; ++h) {
        aZ[h]  = MFMA(na[h][ks], b0, aZ[h]);
        aR[h]  = MFMA(na[h][ks], b1, aR[h]);
        aNa[h] = MFMA(na[h][ks], b2, aNa[h]);
      }
    }
    // elementwise + store
    int c = t * 16 + cl;
    bool valid = c < H_DIM;
    #pragma unroll
    for (int h = 0; h < 2; ++h) {
      #pragma unroll
      for (int r = 0; r < 4; ++r) {
        int row = h * 16 + q * 4 + r;
        float hpv = valid ? hp_g[(size_t)(rowbase + row) * H_DIM + c] : 0.f;
        float z2 = sigmoidf_(aZ[h][r]);
        float r2 = sigmoidf_(aR[h][r]);
        float nm = tanhf_(aNa[h][r] + r2 * aNb[h][r]);
        float hnew = (1.f - z2) * nm + z2 * hpv;
        if (valid) out[(size_t)(rowbase + row) * H_DIM + c] = hnew;
      }
    }
  }
}

extern "C" void kernel_launch(void* const* d_in, const int* in_sizes, int n_in,
                              void* d_out, int out_size, void* d_ws, size_t ws_size,
                              hipStream_t stream) {
  const float* x    = (const float*)d_in[0];
  const float* h_p  = (const float*)d_in[1];
  const float* h_s  = (const float*)d_in[2];
  const float* Wi   = (const float*)d_in[3];
  const float* Wh   = (const float*)d_in[4];
  const float* bi   = (const float*)d_in[5];
  const float* bh   = (const float*)d_in[6];
  const float* W_z  = (const float*)d_in[7];
  const float* U_z  = (const float*)d_in[8];
  const float* Us_z = (const float*)d_in[9];
  const float* W_r  = (const float*)d_in[10];
  const float* U_r  = (const float*)d_in[11];
  const float* Us_r = (const float*)d_in[12];
  const float* W_hn = (const float*)d_in[13];
  const float* U_hn = (const float*)d_in[14];
  const float* Us_hn= (const float*)d_in[15];
  uint16_t* ws = (uint16_t*)d_ws;
  float* out = (float*)d_out;

  int rows = in_sizes[0] / D_IN;          // 262144
  prepack_kernel<<<(TOTAL_E + 255) / 256, 256, 0, stream>>>(
      Wi, Wh, W_z, U_z, Us_z, W_r, U_r, Us_r, W_hn, U_hn, Us_hn, bi, bh, ws);
  gru_fused<<<rows / BM, NTHREADS, 0, stream>>>(x, h_p, h_s, ws, out);
}

// Round 6
// 373.030 us; speedup vs baseline: 7.7945x; 1.0150x over previous
//
#include <hip/hip_runtime.h>
#include <stdint.h>

#define D_IN 250
#define H_DIM 100
#define RPW 32            // rows per wave
#define NTHREADS 256      // 4 waves
#define BM (4*RPW)        // 128 rows per block

// ws layout: 588 fragments of 512 bf16 elems each.
// pass1 frag id = t*36 + ks*3 + g      (t 0..6, ks 0..11 [0-7 X, 8-11 Hs], g 0..2 [r,z,n])
// pass2 frag id = 252 + t*48 + ks*3+g  (ks 0..15 [0-7 X, 8-11 Hp, 12-15 HsN], g [z,r,hn])
#define P2_FRAG 252
#define TOTAL_E ((252 + 336) * 512)     // 301056 elems

typedef __bf16 bf16x8 __attribute__((ext_vector_type(8)));
typedef float f32x4 __attribute__((ext_vector_type(4)));

static __device__ __forceinline__ uint16_t f2bf(float f) {
  uint32_t u = __builtin_bit_cast(uint32_t, f);
  u = (u + 0x7FFFu + ((u >> 16) & 1u)) >> 16;
  return (uint16_t)u;
}
static __device__ __forceinline__ float sigmoidf_(float x) {
  return 1.0f / (1.0f + __expf(-x));
}
static __device__ __forceinline__ float tanhf_(float x) {
  return 2.0f / (1.0f + __expf(-2.0f * x)) - 1.0f;
}

// ---------------- weight prepack: fp32 -> bf16 B-fragment layout -------------
// within a frag: [lane(64)][j(8)]; k_loc=(lane>>4)*8+j, col c = t*16+(lane&15)
// bias folded: pass1 X k==250 -> bi ; pass1 Hs k==100 -> bh ; pass2 -> 0
__global__ void prepack_kernel(const float* __restrict__ Wi, const float* __restrict__ Wh,
                               const float* __restrict__ W_z, const float* __restrict__ U_z,
                               const float* __restrict__ Us_z, const float* __restrict__ W_r,
                               const float* __restrict__ U_r, const float* __restrict__ Us_r,
                               const float* __restrict__ W_hn, const float* __restrict__ U_hn,
                               const float* __restrict__ Us_hn, const float* __restrict__ bi,
                               const float* __restrict__ bh, uint16_t* __restrict__ ws) {
  int idx = blockIdx.x * blockDim.x + threadIdx.x;
  if (idx >= TOTAL_E) return;
  int f = idx >> 9;
  int a = idx & 511;
  int lane = a >> 3, j = a & 7;
  int kloc = ((lane >> 4) << 3) + j;
  int cl = lane & 15;
  float val = 0.f;
  if (f < P2_FRAG) {
    int g = f % 3, ks = (f / 3) % 12, t = f / 36;
    int c = t * 16 + cl;
    if (c < H_DIM) {
      if (ks < 8) {
        int k = ks * 32 + kloc;
        if (k < D_IN)       val = Wi[(size_t)(g * H_DIM + c) * D_IN + k];
        else if (k == D_IN) val = bi[g * H_DIM + c];
      } else {
        int k = (ks - 8) * 32 + kloc;
        if (k < H_DIM)       val = Wh[(size_t)(g * H_DIM + c) * H_DIM + k];
        else if (k == H_DIM) val = bh[g * H_DIM + c];
      }
    }
  } else {
    int f2 = f - P2_FRAG;
    int g = f2 % 3, ks = (f2 / 3) % 16, t = f2 / 48;
    int c = t * 16 + cl;
    if (c < H_DIM) {
      if (ks < 8) {
        int k = ks * 32 + kloc;
        const float* W = g == 0 ? W_z : g == 1 ? W_r : W_hn;
        if (k < D_IN) val = W[(size_t)c * D_IN + k];
      } else if (ks < 12) {
        int k = (ks - 8) * 32 + kloc;
        const float* W = g == 0 ? U_z : g == 1 ? U_r : U_hn;
        if (k < H_DIM) val = W[(size_t)c * H_DIM + k];
      } else {
        int k = (ks - 12) * 32 + kloc;
        const float* W = g == 0 ? Us_z : g == 1 ? Us_r : Us_hn;
        if (k < H_DIM) val = W[(size_t)c * H_DIM + k];
      }
    }
  }
  ws[idx] = f2bf(val);
}

// ------------------------- A-fragment direct loaders -------------------------
static __device__ __forceinline__ bf16x8 xfrag(const float* __restrict__ xr, int ks, int q) {
  int c0 = ks * 32 + q * 8;
  bf16x8 a;
  if (c0 < 248) {
    #pragma unroll
    for (int i = 0; i < 4; ++i) {
      float2 f = *(const float2*)(xr + c0 + 2 * i);
      a[2 * i] = (__bf16)f.x; a[2 * i + 1] = (__bf16)f.y;
    }
  } else {                    // cols 248,249 valid; 250 = bias 1.0; rest 0
    float2 f = *(const float2*)(xr + 248);
    a[0] = (__bf16)f.x; a[1] = (__bf16)f.y; a[2] = (__bf16)1.0f;
    a[3] = (__bf16)0.0f; a[4] = (__bf16)0.0f; a[5] = (__bf16)0.0f;
    a[6] = (__bf16)0.0f; a[7] = (__bf16)0.0f;
  }
  return a;
}
static __device__ __forceinline__ bf16x8 hfrag(const float* __restrict__ hr, int ks, int q, float bias) {
  int c0 = ks * 32 + q * 8;
  bf16x8 a;
  #pragma unroll
  for (int i = 0; i < 8; ++i) a[i] = (__bf16)0.0f;
  if (c0 <= 88) {
    #pragma unroll
    for (int i = 0; i < 4; ++i) {
      float2 f = *(const float2*)(hr + c0 + 2 * i);
      a[2 * i] = (__bf16)f.x; a[2 * i + 1] = (__bf16)f.y;
    }
  } else if (c0 == 96) {      // cols 96..99 valid; 100 = bias; rest 0
    float2 f0 = *(const float2*)(hr + 96);
    float2 f1 = *(const float2*)(hr + 98);
    a[0] = (__bf16)f0.x; a[1] = (__bf16)f0.y; a[2] = (__bf16)f1.x; a[3] = (__bf16)f1.y;
    a[4] = (__bf16)bias;
  }
  return a;
}

#define MFMA(A, B, C) __builtin_amdgcn_mfma_f32_16x16x32_bf16((A), (B), (C), 0, 0, 0)

// ---------------------------- fused GRU kernel -------------------------------
// nt-outer / K-inner, A cached in registers, B software-pipelined at depth 4
// K-steps (12 fragments in flight). Wave-private LDS slab for HsNew. 0 barriers.
__global__ __launch_bounds__(NTHREADS, 2) void gru_fused(
    const float* __restrict__ x, const float* __restrict__ hp_g,
    const float* __restrict__ hs_g, const uint16_t* __restrict__ ws,
    float* __restrict__ out) {
  __shared__ __align__(16) uint16_t ldsT[4 * RPW * 128];   // 32 KB, wave-private slabs

  const int tid = threadIdx.x;
  const int lane = tid & 63, wid = tid >> 6;
  const int q = lane >> 4, cl = lane & 15;
  const int rowbase = blockIdx.x * BM + wid * RPW;   // this wave's first global row
  uint16_t* lT = ldsT + wid * RPW * 128;

  // zero pad-cols 112..127 of the transpose slab (read by pass2 ks=15 frags)
  {
    int r0 = lane >> 1;
    int col = 112 + (lane & 1) * 8;
    int bo = r0 * 256 + ((col * 2) ^ ((r0 & 7) << 4));
    uint4 z; z.x = 0; z.y = 0; z.z = 0; z.w = 0;
    *(uint4*)((char*)lT + bo) = z;
  }

  // ---- load & convert A fragments (held in registers across all tiles) ----
  bf16x8 xa[2][8], ha[2][4];
  #pragma unroll
  for (int h = 0; h < 2; ++h) {
    const float* xr = x + (size_t)(rowbase + h * 16 + cl) * D_IN;
    #pragma unroll
    for (int ks = 0; ks < 8; ++ks) xa[h][ks] = xfrag(xr, ks, q);
    const float* hr = hs_g + (size_t)(rowbase + h * 16 + cl) * H_DIM;
    #pragma unroll
    for (int ks = 0; ks < 4; ++ks) ha[h][ks] = hfrag(hr, ks, q, 1.0f);
  }

  const uint16_t* wsl = ws + lane * 8;

  // =========================== PASS 1 (GRU cell) ============================
  #pragma unroll 1
  for (int t = 0; t < 7; ++t) {
    f32x4 aR[2], aZ[2], aNi[2], aNh[2];
    #pragma unroll
    for (int h = 0; h < 2; ++h) { aR[h] = (f32x4)(0.f); aZ[h] = (f32x4)(0.f); aNi[h] = (f32x4)(0.f); aNh[h] = (f32x4)(0.f); }
    const uint16_t* bp = wsl + (size_t)t * (36 * 512);

    bf16x8 pb[4][3];                       // rotating prefetch buffer (static idx)
    #pragma unroll
    for (int p = 0; p < 4; ++p) {
      #pragma unroll
      for (int g = 0; g < 3; ++g) pb[p][g] = *(const bf16x8*)(bp + (p * 3 + g) * 512);
    }
    #pragma unroll
    for (int ks = 0; ks < 12; ++ks) {
      const int slot = ks & 3;
      bf16x8 b0 = pb[slot][0], b1 = pb[slot][1], b2 = pb[slot][2];
      if (ks < 8) {                        // prefetch ks+4
        #pragma unroll
        for (int g = 0; g < 3; ++g) pb[slot][g] = *(const bf16x8*)(bp + ((ks + 4) * 3 + g) * 512);
      }
      #pragma unroll
      for (int h = 0; h < 2; ++h) {
        bf16x8 a = (ks < 8) ? xa[h][ks] : ha[h][ks - 8];
        aR[h] = MFMA(a, b0, aR[h]);
        aZ[h] = MFMA(a, b1, aZ[h]);
        if (ks < 8) aNi[h] = MFMA(a, b2, aNi[h]);
        else        aNh[h] = MFMA(a, b2, aNh[h]);
      }
    }

    // elementwise -> HsNew tile into LDS (cols >=100 compute exactly 0)
    int c = t * 16 + cl;
    bool valid = c < H_DIM;
    #pragma unroll
    for (int h = 0; h < 2; ++h) {
      #pragma unroll
      for (int r = 0; r < 4; ++r) {
        int row = h * 16 + q * 4 + r;
        float hsp = valid ? hs_g[(size_t)(rowbase + row) * H_DIM + c] : 0.f;
        float rr = sigmoidf_(aR[h][r]);
        float zz = sigmoidf_(aZ[h][r]);
        float nn = tanhf_(aNi[h][r] + rr * aNh[h][r]);
        float hsn = (1.f - zz) * nn + zz * hsp;
        int bo = row * 256 + ((c * 2) ^ ((row & 7) << 4));
        *(uint16_t*)((char*)lT + bo) = f2bf(hsn);
      }
    }
  }

  // ---- load Hp fragments; read HsNew fragments back (wave-private, no barrier) ----
  bf16x8 pa[2][4], na[2][4];
  #pragma unroll
  for (int h = 0; h < 2; ++h) {
    const float* pr = hp_g + (size_t)(rowbase + h * 16 + cl) * H_DIM;
    #pragma unroll
    for (int ks = 0; ks < 4; ++ks) pa[h][ks] = hfrag(pr, ks, q, 0.0f);
  }
  #pragma unroll
  for (int h = 0; h < 2; ++h) {
    int row = h * 16 + cl;
    #pragma unroll
    for (int ks = 0; ks < 4; ++ks) {
      int bo = row * 256 + (((ks * 64) + q * 16) ^ ((row & 7) << 4));
      na[h][ks] = *(const bf16x8*)((const char*)lT + bo);
    }
  }

  // =========================== PASS 2 (task head) ===========================
  #pragma unroll 1
  for (int t = 0; t < 7; ++t) {
    f32x4 aZ[2], aR[2], aNa[2], aNb[2];
    #pragma unroll
    for (int h = 0; h < 2; ++h) { aZ[h] = (f32x4)(0.f); aR[h] = (f32x4)(0.f); aNa[h] = (f32x4)(0.f); aNb[h] = (f32x4)(0.f); }
    const uint16_t* bp = wsl + (size_t)(P2_FRAG * 512) + (size_t)t * (48 * 512);

    bf16x8 pb[4][3];
    #pragma unroll
    for (int p = 0; p < 4; ++p) {
      #pragma unroll
      for (int g = 0; g < 3; ++g) pb[p][g] = *(const bf16x8*)(bp + (p * 3 + g) * 512);
    }
    #pragma unroll
    for (int ks = 0; ks < 16; ++ks) {
      const int slot = ks & 3;
      bf16x8 b0 = pb[slot][0], b1 = pb[slot][1], b2 = pb[slot][2];
      if (ks < 12) {                       // prefetch ks+4
        #pragma unroll
        for (int g = 0; g < 3; ++g) pb[slot][g] = *(const bf16x8*)(bp + ((ks + 4) * 3 + g) * 512);
      }
      #pragma unroll
      for (int h = 0; h < 2; ++h) {
        bf16x8 a = (ks < 8) ? xa[h][ks] : (ks < 12) ? pa[h][ks - 8] : na[h][ks - 12];
        aZ[h] = MFMA(a, b0, aZ[h]);
        aR[h] = MFMA(a, b1, aR[h]);
        if (ks < 8)       aNa[h] = MFMA(a, b2, aNa[h]);
        else if (ks < 12) aNb[h] = MFMA(a, b2, aNb[h]);
        else              aNa[h] = MFMA(a, b2, aNa[h]);
      }
    }

    // elementwise + store
    int c = t * 16 + cl;
    bool valid = c < H_DIM;
    #pragma unroll
    for (int h = 0; h < 2; ++h) {
      #pragma unroll
      for (int r = 0; r < 4; ++r) {
        int row = h * 16 + q * 4 + r;
        float hpv = valid ? hp_g[(size_t)(rowbase + row) * H_DIM + c] : 0.f;
        float z2 = sigmoidf_(aZ[h][r]);
        float r2 = sigmoidf_(aR[h][r]);
        float nm = tanhf_(aNa[h][r] + r2 * aNb[h][r]);
        float hnew = (1.f - z2) * nm + z2 * hpv;
        if (valid) out[(size_t)(rowbase + row) * H_DIM + c] = hnew;
      }
    }
  }
}

extern "C" void kernel_launch(void* const* d_in, const int* in_sizes, int n_in,
                              void* d_out, int out_size, void* d_ws, size_t ws_size,
                              hipStream_t stream) {
  const float* x    = (const float*)d_in[0];
  const float* h_p  = (const float*)d_in[1];
  const float* h_s  = (const float*)d_in[2];
  const float* Wi   = (const float*)d_in[3];
  const float* Wh   = (const float*)d_in[4];
  const float* bi   = (const float*)d_in[5];
  const float* bh   = (const float*)d_in[6];
  const float* W_z  = (const float*)d_in[7];
  const float* U_z  = (const float*)d_in[8];
  const float* Us_z = (const float*)d_in[9];
  const float* W_r  = (const float*)d_in[10];
  const float* U_r  = (const float*)d_in[11];
  const float* Us_r = (const float*)d_in[12];
  const float* W_hn = (const float*)d_in[13];
  const float* U_hn = (const float*)d_in[14];
  const float* Us_hn= (const float*)d_in[15];
  uint16_t* ws = (uint16_t*)d_ws;
  float* out = (float*)d_out;

  int rows = in_sizes[0] / D_IN;          // 262144
  prepack_kernel<<<(TOTAL_E + 255) / 256, 256, 0, stream>>>(
      Wi, Wh, W_z, U_z, Us_z, W_r, U_r, Us_r, W_hn, U_hn, Us_hn, bi, bh, ws);
  gru_fused<<<rows / BM, NTHREADS, 0, stream>>>(x, h_p, h_s, ws, out);
}

// Round 7
// 325.367 us; speedup vs baseline: 8.9363x; 1.1465x over previous
//
#include <hip/hip_runtime.h>
#include <stdint.h>

#define D_IN 250
#define H_DIM 100
#define RPW 32            // rows per wave
#define NTHREADS 256      // 4 waves
#define BM (4*RPW)        // 128 rows per block

// ws layout: 588 fragments of 512 bf16 elems each.
// pass1 frag id = t*36 + ks*3 + g      (t 0..6, ks 0..11 [0-7 X, 8-11 Hs], g 0..2 [r,z,n])
// pass2 frag id = 252 + t*48 + ks*3+g  (ks 0..15 [0-7 X, 8-11 Hp, 12-15 HsN], g [z,r,hn])
#define P2_FRAG 252
#define TOTAL_E ((252 + 336) * 512)     // 301056 elems

typedef __bf16 bf16x8 __attribute__((ext_vector_type(8)));
typedef float f32x4 __attribute__((ext_vector_type(4)));

static __device__ __forceinline__ uint16_t f2bf(float f) {
  uint32_t u = __builtin_bit_cast(uint32_t, f);
  u = (u + 0x7FFFu + ((u >> 16) & 1u)) >> 16;
  return (uint16_t)u;
}
static __device__ __forceinline__ float bf2f(uint16_t h) {
  uint32_t u = ((uint32_t)h) << 16;
  return __builtin_bit_cast(float, u);
}
static __device__ __forceinline__ float sigmoidf_(float x) {
  return 1.0f / (1.0f + __expf(-x));
}
static __device__ __forceinline__ float tanhf_(float x) {
  return 2.0f / (1.0f + __expf(-2.0f * x)) - 1.0f;
}

// ---------------- weight prepack: fp32 -> bf16 B-fragment layout -------------
__global__ void prepack_kernel(const float* __restrict__ Wi, const float* __restrict__ Wh,
                               const float* __restrict__ W_z, const float* __restrict__ U_z,
                               const float* __restrict__ Us_z, const float* __restrict__ W_r,
                               const float* __restrict__ U_r, const float* __restrict__ Us_r,
                               const float* __restrict__ W_hn, const float* __restrict__ U_hn,
                               const float* __restrict__ Us_hn, const float* __restrict__ bi,
                               const float* __restrict__ bh, uint16_t* __restrict__ ws) {
  int idx = blockIdx.x * blockDim.x + threadIdx.x;
  if (idx >= TOTAL_E) return;
  int f = idx >> 9;
  int a = idx & 511;
  int lane = a >> 3, j = a & 7;
  int kloc = ((lane >> 4) << 3) + j;
  int cl = lane & 15;
  float val = 0.f;
  if (f < P2_FRAG) {
    int g = f % 3, ks = (f / 3) % 12, t = f / 36;
    int c = t * 16 + cl;
    if (c < H_DIM) {
      if (ks < 8) {
        int k = ks * 32 + kloc;
        if (k < D_IN)       val = Wi[(size_t)(g * H_DIM + c) * D_IN + k];
        else if (k == D_IN) val = bi[g * H_DIM + c];
      } else {
        int k = (ks - 8) * 32 + kloc;
        if (k < H_DIM)       val = Wh[(size_t)(g * H_DIM + c) * H_DIM + k];
        else if (k == H_DIM) val = bh[g * H_DIM + c];
      }
    }
  } else {
    int f2 = f - P2_FRAG;
    int g = f2 % 3, ks = (f2 / 3) % 16, t = f2 / 48;
    int c = t * 16 + cl;
    if (c < H_DIM) {
      if (ks < 8) {
        int k = ks * 32 + kloc;
        const float* W = g == 0 ? W_z : g == 1 ? W_r : W_hn;
        if (k < D_IN) val = W[(size_t)c * D_IN + k];
      } else if (ks < 12) {
        int k = (ks - 8) * 32 + kloc;
        const float* W = g == 0 ? U_z : g == 1 ? U_r : U_hn;
        if (k < H_DIM) val = W[(size_t)c * H_DIM + k];
      } else {
        int k = (ks - 12) * 32 + kloc;
        const float* W = g == 0 ? Us_z : g == 1 ? Us_r : Us_hn;
        if (k < H_DIM) val = W[(size_t)c * H_DIM + k];
      }
    }
  }
  ws[idx] = f2bf(val);
}

// ------------------------- A-fragment direct loaders -------------------------
static __device__ __forceinline__ bf16x8 xfrag(const float* __restrict__ xr, int ks, int q) {
  int c0 = ks * 32 + q * 8;
  bf16x8 a;
  if (c0 < 248) {
    #pragma unroll
    for (int i = 0; i < 4; ++i) {
      float2 f = *(const float2*)(xr + c0 + 2 * i);
      a[2 * i] = (__bf16)f.x; a[2 * i + 1] = (__bf16)f.y;
    }
  } else {                    // cols 248,249 valid; 250 = bias 1.0; rest 0
    float2 f = *(const float2*)(xr + 248);
    a[0] = (__bf16)f.x; a[1] = (__bf16)f.y; a[2] = (__bf16)1.0f;
    a[3] = (__bf16)0.0f; a[4] = (__bf16)0.0f; a[5] = (__bf16)0.0f;
    a[6] = (__bf16)0.0f; a[7] = (__bf16)0.0f;
  }
  return a;
}
static __device__ __forceinline__ bf16x8 hfrag(const float* __restrict__ hr, int ks, int q, float bias) {
  int c0 = ks * 32 + q * 8;
  bf16x8 a;
  #pragma unroll
  for (int i = 0; i < 8; ++i) a[i] = (__bf16)0.0f;
  if (c0 <= 88) {
    #pragma unroll
    for (int i = 0; i < 4; ++i) {
      float2 f = *(const float2*)(hr + c0 + 2 * i);
      a[2 * i] = (__bf16)f.x; a[2 * i + 1] = (__bf16)f.y;
    }
  } else if (c0 == 96) {      // cols 96..99 valid; 100 = bias; rest 0
    float2 f0 = *(const float2*)(hr + 96);
    float2 f1 = *(const float2*)(hr + 98);
    a[0] = (__bf16)f0.x; a[1] = (__bf16)f0.y; a[2] = (__bf16)f1.x; a[3] = (__bf16)f1.y;
    a[4] = (__bf16)bias;
  }
  return a;
}

#define MFMA(A, B, C) __builtin_amdgcn_mfma_f32_16x16x32_bf16((A), (B), (C), 0, 0, 0)

// --------- wave-private B prefetch ring: global -> LDS, no VGPR cost ---------
typedef const __attribute__((address_space(1))) unsigned int* gp1_t;
typedef __attribute__((address_space(3))) unsigned int* lp3_t;

static __device__ __forceinline__ void issue3(const uint16_t* gsrc0, uint16_t* lslot) {
  #pragma unroll
  for (int g = 0; g < 3; ++g) {
    // per-lane global src (includes lane*8); LDS dest = wave-uniform base + lane*16
    __builtin_amdgcn_global_load_lds((gp1_t)(gsrc0 + g * 512), (lp3_t)(lslot + g * 512), 16, 0, 0);
  }
}
#define WAIT_VM9  asm volatile("s_waitcnt vmcnt(9)" ::: "memory")
#define WAIT_LGKM0 asm volatile("s_waitcnt lgkmcnt(0)" ::: "memory")

// ---------------------------- fused GRU kernel -------------------------------
// nt-outer / K-inner; A in registers; B streamed through a 4-slot wave-private
// LDS ring (global_load_lds + counted vmcnt). Hs/Hp elementwise values served
// from the LDS slab so no late global loads pollute the vmcnt ring. 0 barriers.
__global__ __launch_bounds__(NTHREADS, 2) void gru_fused(
    const float* __restrict__ x, const float* __restrict__ hp_g,
    const float* __restrict__ hs_g, const uint16_t* __restrict__ ws,
    float* __restrict__ out) {
  __shared__ __align__(16) uint16_t ldsT[4 * RPW * 128];      // 32 KB: Hs->HsNew, then Hp
  __shared__ __align__(16) uint16_t ldsRing[4 * 4 * 1536];    // 48 KB: [wave][slot 0..3][3 frags]

  const int tid = threadIdx.x;
  const int lane = tid & 63, wid = tid >> 6;
  const int q = lane >> 4, cl = lane & 15;
  const int rowbase = blockIdx.x * BM + wid * RPW;
  uint16_t* lT = ldsT + wid * (RPW * 128);
  uint16_t* ring = ldsRing + wid * (4 * 1536);
  const uint16_t* wsl = ws + lane * 8;

  // ---- prologue: load ALL A fragments (xa, ha, pa) ----
  bf16x8 xa[2][8], ha[2][4], pa[2][4];
  #pragma unroll
  for (int h = 0; h < 2; ++h) {
    const float* xr = x + (size_t)(rowbase + h * 16 + cl) * D_IN;
    #pragma unroll
    for (int ks = 0; ks < 8; ++ks) xa[h][ks] = xfrag(xr, ks, q);
    const float* hr = hs_g + (size_t)(rowbase + h * 16 + cl) * H_DIM;
    #pragma unroll
    for (int ks = 0; ks < 4; ++ks) ha[h][ks] = hfrag(hr, ks, q, 1.0f);
    const float* pr = hp_g + (size_t)(rowbase + h * 16 + cl) * H_DIM;
    #pragma unroll
    for (int ks = 0; ks < 4; ++ks) pa[h][ks] = hfrag(pr, ks, q, 0.0f);
  }

  // stage Hs (bf16) into lT in the A-layout (swizzled); elementwise reads hsp here
  #pragma unroll
  for (int h = 0; h < 2; ++h) {
    int row = h * 16 + cl;
    #pragma unroll
    for (int ks = 0; ks < 4; ++ks) {
      int bo = row * 256 + (((ks * 64) + q * 16) ^ ((row & 7) << 4));
      *(bf16x8*)((char*)lT + bo) = ha[h][ks];
    }
  }

  // ring prologue: slots for consumptions 0,1,2 (pass1 t=0 ks=0..2)
  issue3(wsl + 0 * 512, ring + 0 * 1536);
  issue3(wsl + 3 * 512, ring + 1 * 1536);
  issue3(wsl + 6 * 512, ring + 2 * 1536);

  // =========================== PASS 1 (GRU cell) ============================
  #pragma unroll 1
  for (int t = 0; t < 7; ++t) {
    f32x4 aR[2], aZ[2], aNi[2], aNh[2];
    #pragma unroll
    for (int h = 0; h < 2; ++h) { aR[h] = (f32x4)(0.f); aZ[h] = (f32x4)(0.f); aNi[h] = (f32x4)(0.f); aNh[h] = (f32x4)(0.f); }
    #pragma unroll
    for (int ks = 0; ks < 12; ++ks) {
      int fidn;
      if (ks < 9)      fidn = t * 36 + (ks + 3) * 3;
      else if (t < 6)  fidn = (t + 1) * 36 + (ks - 9) * 3;
      else             fidn = P2_FRAG + (ks - 9) * 3;
      WAIT_LGKM0;                                     // slot being refilled fully read
      issue3(wsl + (size_t)fidn * 512, ring + ((ks + 3) & 3) * 1536);
      WAIT_VM9;                                       // slot ks's 3 loads landed
      const uint16_t* sp = ring + (ks & 3) * 1536 + lane * 8;
      bf16x8 b0 = *(const bf16x8*)(sp);
      bf16x8 b1 = *(const bf16x8*)(sp + 512);
      bf16x8 b2 = *(const bf16x8*)(sp + 1024);
      #pragma unroll
      for (int h = 0; h < 2; ++h) {
        bf16x8 av = (ks < 8) ? xa[h][ks] : ha[h][ks - 8];
        aR[h] = MFMA(av, b0, aR[h]);
        aZ[h] = MFMA(av, b1, aZ[h]);
        if (ks < 8) aNi[h] = MFMA(av, b2, aNi[h]);
        else        aNh[h] = MFMA(av, b2, aNh[h]);
      }
    }
    // elementwise GRU cell -> HsNew written in place into lT (bf16)
    int c = t * 16 + cl;
    #pragma unroll
    for (int h = 0; h < 2; ++h) {
      #pragma unroll
      for (int r = 0; r < 4; ++r) {
        int row = h * 16 + q * 4 + r;
        int bo = row * 256 + ((c * 2) ^ ((row & 7) << 4));
        float hsp = bf2f(*(const uint16_t*)((const char*)lT + bo));
        float rr = sigmoidf_(aR[h][r]);
        float zz = sigmoidf_(aZ[h][r]);
        float nn = tanhf_(aNi[h][r] + rr * aNh[h][r]);
        float hsn = (1.f - zz) * nn + zz * hsp;
        *(uint16_t*)((char*)lT + bo) = f2bf(hsn);
      }
    }
  }

  // ---- boundary: HsNew frags out of lT, then stage Hp into lT (pure LDS) ----
  bf16x8 na[2][4];
  #pragma unroll
  for (int h = 0; h < 2; ++h) {
    int row = h * 16 + cl;
    #pragma unroll
    for (int ks = 0; ks < 4; ++ks) {
      int bo = row * 256 + (((ks * 64) + q * 16) ^ ((row & 7) << 4));
      na[h][ks] = *(const bf16x8*)((const char*)lT + bo);
    }
  }
  WAIT_LGKM0;                                         // na in regs before overwrite
  #pragma unroll
  for (int h = 0; h < 2; ++h) {
    int row = h * 16 + cl;
    #pragma unroll
    for (int ks = 0; ks < 4; ++ks) {
      int bo = row * 256 + (((ks * 64) + q * 16) ^ ((row & 7) << 4));
      *(bf16x8*)((char*)lT + bo) = pa[h][ks];
    }
  }

  // =========================== PASS 2 (task head) ===========================
  #pragma unroll 1
  for (int t = 0; t < 7; ++t) {
    f32x4 aZ[2], aR[2], aNa[2], aNb[2];
    #pragma unroll
    for (int h = 0; h < 2; ++h) { aZ[h] = (f32x4)(0.f); aR[h] = (f32x4)(0.f); aNa[h] = (f32x4)(0.f); aNb[h] = (f32x4)(0.f); }
    #pragma unroll
    for (int ks = 0; ks < 16; ++ks) {
      int fidn;
      if (ks < 13)     fidn = P2_FRAG + t * 48 + (ks + 3) * 3;
      else if (t < 6)  fidn = P2_FRAG + (t + 1) * 48 + (ks - 13) * 3;
      else             fidn = P2_FRAG + 6 * 48 + 45;  // tail clamp: harmless refill
      WAIT_LGKM0;
      issue3(wsl + (size_t)fidn * 512, ring + ((ks + 3) & 3) * 1536);
      WAIT_VM9;
      const uint16_t* sp = ring + (ks & 3) * 1536 + lane * 8;
      bf16x8 b0 = *(const bf16x8*)(sp);
      bf16x8 b1 = *(const bf16x8*)(sp + 512);
      bf16x8 b2 = *(const bf16x8*)(sp + 1024);
      #pragma unroll
      for (int h = 0; h < 2; ++h) {
        bf16x8 av = (ks < 8) ? xa[h][ks] : (ks < 12) ? pa[h][ks - 8] : na[h][ks - 12];
        aZ[h] = MFMA(av, b0, aZ[h]);
        aR[h] = MFMA(av, b1, aR[h]);
        if (ks < 8)       aNa[h] = MFMA(av, b2, aNa[h]);
        else if (ks < 12) aNb[h] = MFMA(av, b2, aNb[h]);
        else              aNa[h] = MFMA(av, b2, aNa[h]);
      }
    }
    // elementwise + store (hpv from lT)
    int c = t * 16 + cl;
    bool valid = c < H_DIM;
    #pragma unroll
    for (int h = 0; h < 2; ++h) {
      #pragma unroll
      for (int r = 0; r < 4; ++r) {
        int row = h * 16 + q * 4 + r;
        int bo = row * 256 + ((c * 2) ^ ((row & 7) << 4));
        float hpv = bf2f(*(const uint16_t*)((const char*)lT + bo));
        float z2 = sigmoidf_(aZ[h][r]);
        float r2 = sigmoidf_(aR[h][r]);
        float nm = tanhf_(aNa[h][r] + r2 * aNb[h][r]);
        float hnew = (1.f - z2) * nm + z2 * hpv;
        if (valid) out[(size_t)(rowbase + row) * H_DIM + c] = hnew;
      }
    }
  }
}

extern "C" void kernel_launch(void* const* d_in, const int* in_sizes, int n_in,
                              void* d_out, int out_size, void* d_ws, size_t ws_size,
                              hipStream_t stream) {
  const float* x    = (const float*)d_in[0];
  const float* h_p  = (const float*)d_in[1];
  const float* h_s  = (const float*)d_in[2];
  const float* Wi   = (const float*)d_in[3];
  const float* Wh   = (const float*)d_in[4];
  const float* bi   = (const float*)d_in[5];
  const float* bh   = (const float*)d_in[6];
  const float* W_z  = (const float*)d_in[7];
  const float* U_z  = (const float*)d_in[8];
  const float* Us_z = (const float*)d_in[9];
  const float* W_r  = (const float*)d_in[10];
  const float* U_r  = (const float*)d_in[11];
  const float* Us_r = (const float*)d_in[12];
  const float* W_hn = (const float*)d_in[13];
  const float* U_hn = (const float*)d_in[14];
  const float* Us_hn= (const float*)d_in[15];
  uint16_t* ws = (uint16_t*)d_ws;
  float* out = (float*)d_out;

  int rows = in_sizes[0] / D_IN;          // 262144
  prepack_kernel<<<(TOTAL_E + 255) / 256, 256, 0, stream>>>(
      Wi, Wh, W_z, U_z, Us_z, W_r, U_r, Us_r, W_hn, U_hn, Us_hn, bi, bh, ws);
  gru_fused<<<rows / BM, NTHREADS, 0, stream>>>(x, h_p, h_s, ws, out);
}

// Round 8
// 272.013 us; speedup vs baseline: 10.6891x; 1.1961x over previous
//
#include <hip/hip_runtime.h>
#include <stdint.h>

#define D_IN 250
#define H_DIM 100
#define RPW 32            // rows per wave
#define NTHREADS 256      // 4 waves
#define BM (4*RPW)        // 128 rows per block

// ws layout: 588 fragments of 512 bf16 elems each.
// pass1 frag id = t*36 + ks*3 + g      (t 0..6, ks 0..11 [0-7 X, 8-11 Hs], g 0..2 [r,z,n])
// pass2 frag id = 252 + t*48 + ks*3+g  (ks 0..15 [0-7 X, 8-11 Hp, 12-15 HsN], g [z,r,hn])
#define P2_FRAG 252
#define TOTAL_E ((252 + 336) * 512)     // 301056 elems

typedef __bf16 bf16x8 __attribute__((ext_vector_type(8)));
typedef float f32x4 __attribute__((ext_vector_type(4)));

static __device__ __forceinline__ uint16_t f2bf(float f) {
  uint32_t u = __builtin_bit_cast(uint32_t, f);
  u = (u + 0x7FFFu + ((u >> 16) & 1u)) >> 16;
  return (uint16_t)u;
}
static __device__ __forceinline__ float bf2f(uint16_t h) {
  uint32_t u = ((uint32_t)h) << 16;
  return __builtin_bit_cast(float, u);
}
static __device__ __forceinline__ float sigmoidf_(float x) {
  return 1.0f / (1.0f + __expf(-x));
}
static __device__ __forceinline__ float tanhf_(float x) {
  return 2.0f / (1.0f + __expf(-2.0f * x)) - 1.0f;
}

// ---------------- weight prepack: fp32 -> bf16 B-fragment layout -------------
__global__ void prepack_kernel(const float* __restrict__ Wi, const float* __restrict__ Wh,
                               const float* __restrict__ W_z, const float* __restrict__ U_z,
                               const float* __restrict__ Us_z, const float* __restrict__ W_r,
                               const float* __restrict__ U_r, const float* __restrict__ Us_r,
                               const float* __restrict__ W_hn, const float* __restrict__ U_hn,
                               const float* __restrict__ Us_hn, const float* __restrict__ bi,
                               const float* __restrict__ bh, uint16_t* __restrict__ ws) {
  int idx = blockIdx.x * blockDim.x + threadIdx.x;
  if (idx >= TOTAL_E) return;
  int f = idx >> 9;
  int a = idx & 511;
  int lane = a >> 3, j = a & 7;
  int kloc = ((lane >> 4) << 3) + j;
  int cl = lane & 15;
  float val = 0.f;
  if (f < P2_FRAG) {
    int g = f % 3, ks = (f / 3) % 12, t = f / 36;
    int c = t * 16 + cl;
    if (c < H_DIM) {
      if (ks < 8) {
        int k = ks * 32 + kloc;
        if (k < D_IN)       val = Wi[(size_t)(g * H_DIM + c) * D_IN + k];
        else if (k == D_IN) val = bi[g * H_DIM + c];
      } else {
        int k = (ks - 8) * 32 + kloc;
        if (k < H_DIM)       val = Wh[(size_t)(g * H_DIM + c) * H_DIM + k];
        else if (k == H_DIM) val = bh[g * H_DIM + c];
      }
    }
  } else {
    int f2 = f - P2_FRAG;
    int g = f2 % 3, ks = (f2 / 3) % 16, t = f2 / 48;
    int c = t * 16 + cl;
    if (c < H_DIM) {
      if (ks < 8) {
        int k = ks * 32 + kloc;
        const float* W = g == 0 ? W_z : g == 1 ? W_r : W_hn;
        if (k < D_IN) val = W[(size_t)c * D_IN + k];
      } else if (ks < 12) {
        int k = (ks - 8) * 32 + kloc;
        const float* W = g == 0 ? U_z : g == 1 ? U_r : U_hn;
        if (k < H_DIM) val = W[(size_t)c * H_DIM + k];
      } else {
        int k = (ks - 12) * 32 + kloc;
        const float* W = g == 0 ? Us_z : g == 1 ? Us_r : Us_hn;
        if (k < H_DIM) val = W[(size_t)c * H_DIM + k];
      }
    }
  }
  ws[idx] = f2bf(val);
}

// ------------------------- A-fragment direct loaders -------------------------
static __device__ __forceinline__ bf16x8 xfrag(const float* __restrict__ xr, int ks, int q) {
  int c0 = ks * 32 + q * 8;
  bf16x8 a;
  if (c0 < 248) {
    #pragma unroll
    for (int i = 0; i < 4; ++i) {
      float2 f = *(const float2*)(xr + c0 + 2 * i);
      a[2 * i] = (__bf16)f.x; a[2 * i + 1] = (__bf16)f.y;
    }
  } else {                    // cols 248,249 valid; 250 = bias 1.0; rest 0
    float2 f = *(const float2*)(xr + 248);
    a[0] = (__bf16)f.x; a[1] = (__bf16)f.y; a[2] = (__bf16)1.0f;
    a[3] = (__bf16)0.0f; a[4] = (__bf16)0.0f; a[5] = (__bf16)0.0f;
    a[6] = (__bf16)0.0f; a[7] = (__bf16)0.0f;
  }
  return a;
}
static __device__ __forceinline__ bf16x8 hfrag(const float* __restrict__ hr, int ks, int q, float bias) {
  int c0 = ks * 32 + q * 8;
  bf16x8 a;
  #pragma unroll
  for (int i = 0; i < 8; ++i) a[i] = (__bf16)0.0f;
  if (c0 <= 88) {
    #pragma unroll
    for (int i = 0; i < 4; ++i) {
      float2 f = *(const float2*)(hr + c0 + 2 * i);
      a[2 * i] = (__bf16)f.x; a[2 * i + 1] = (__bf16)f.y;
    }
  } else if (c0 == 96) {      // cols 96..99 valid; 100 = bias; rest 0
    float2 f0 = *(const float2*)(hr + 96);
    float2 f1 = *(const float2*)(hr + 98);
    a[0] = (__bf16)f0.x; a[1] = (__bf16)f0.y; a[2] = (__bf16)f1.x; a[3] = (__bf16)f1.y;
    a[4] = (__bf16)bias;
  }
  return a;
}

#define MFMA(A, B, C) __builtin_amdgcn_mfma_f32_16x16x32_bf16((A), (B), (C), 0, 0, 0)

// --------------- block-shared B ring: global -> LDS DMA ----------------------
typedef const __attribute__((address_space(1))) unsigned int* gp1_t;
typedef __attribute__((address_space(3))) unsigned int* lp3_t;

static __device__ __forceinline__ void gload(const uint16_t* gsrc, uint16_t* ldst) {
  __builtin_amdgcn_global_load_lds((gp1_t)gsrc, (lp3_t)ldst, 16, 0, 0);
}
#define WAIT_VM5   asm volatile("s_waitcnt vmcnt(5)" ::: "memory")
#define WAIT_LGKM0 asm volatile("s_waitcnt lgkmcnt(0)" ::: "memory")
#define BAR        do { __builtin_amdgcn_s_barrier(); __builtin_amdgcn_sched_barrier(0); } while (0)

// ---------------------------- fused GRU kernel -------------------------------
// nt-outer / K-inner; A in registers; B streamed through a BLOCK-SHARED 8-slot
// LDS ring: waves 0-2 each DMA one fragment per K-step at depth 6, all 4 waves
// consume. One raw s_barrier per K-step (never __syncthreads -> vmcnt(0)).
__global__ __launch_bounds__(NTHREADS, 2) void gru_fused(
    const float* __restrict__ x, const float* __restrict__ hp_g,
    const float* __restrict__ hs_g, const uint16_t* __restrict__ ws,
    float* __restrict__ out) {
  __shared__ __align__(16) uint16_t ldsT[4 * RPW * 128];   // 32 KB: Hs->HsNew, then Hp
  __shared__ __align__(16) uint16_t ring[8 * 1536];        // 24 KB: 8 slots x 3 frags

  const int tid = threadIdx.x;
  const int lane = tid & 63, wid = tid >> 6;
  const int q = lane >> 4, cl = lane & 15;
  const int rowbase = blockIdx.x * BM + wid * RPW;
  uint16_t* lT = ldsT + wid * (RPW * 128);
  const uint16_t* wsl = ws + lane * 8;

  // ---- prologue: load ALL A fragments (xa, ha, pa) ----
  bf16x8 xa[2][8], ha[2][4], pa[2][4];
  #pragma unroll
  for (int h = 0; h < 2; ++h) {
    const float* xr = x + (size_t)(rowbase + h * 16 + cl) * D_IN;
    #pragma unroll
    for (int ks = 0; ks < 8; ++ks) xa[h][ks] = xfrag(xr, ks, q);
    const float* hr = hs_g + (size_t)(rowbase + h * 16 + cl) * H_DIM;
    #pragma unroll
    for (int ks = 0; ks < 4; ++ks) ha[h][ks] = hfrag(hr, ks, q, 1.0f);
    const float* pr = hp_g + (size_t)(rowbase + h * 16 + cl) * H_DIM;
    #pragma unroll
    for (int ks = 0; ks < 4; ++ks) pa[h][ks] = hfrag(pr, ks, q, 0.0f);
  }

  // stage Hs (bf16) into lT in the A-layout (swizzled); covers cols 0..127
  #pragma unroll
  for (int h = 0; h < 2; ++h) {
    int row = h * 16 + cl;
    #pragma unroll
    for (int ks = 0; ks < 4; ++ks) {
      int bo = row * 256 + (((ks * 64) + q * 16) ^ ((row & 7) << 4));
      *(bf16x8*)((char*)lT + bo) = ha[h][ks];
    }
  }

  // ring prologue: issue steps 0..5 (t=0: fid = s*3 + g), slot = s
  if (wid < 3) {
    #pragma unroll
    for (int s = 0; s < 6; ++s)
      gload(wsl + (size_t)(s * 3 + wid) * 512, ring + s * 1536 + wid * 512);
    WAIT_VM5;
  }
  BAR;

  // =========================== PASS 1 (GRU cell) ============================
  #pragma unroll 1
  for (int t = 0; t < 7; ++t) {
    f32x4 aR[2], aZ[2], aNi[2], aNh[2];
    #pragma unroll
    for (int h = 0; h < 2; ++h) { aR[h] = (f32x4)(0.f); aZ[h] = (f32x4)(0.f); aNi[h] = (f32x4)(0.f); aNh[h] = (f32x4)(0.f); }
    #pragma unroll
    for (int ks = 0; ks < 12; ++ks) {
      // consume slot s = t*12+ks
      const uint16_t* sp = ring + ((t * 12 + ks) & 7) * 1536 + lane * 8;
      bf16x8 b0 = *(const bf16x8*)(sp);
      bf16x8 b1 = *(const bf16x8*)(sp + 512);
      bf16x8 b2 = *(const bf16x8*)(sp + 1024);
      // issue step s+6 into slot (s+6)&7  (ks static -> fid branch folds)
      if (wid < 3) {
        int fid = (ks < 6) ? (t * 36 + (ks + 6) * 3)
                : (t < 6 ? ((t + 1) * 36 + (ks - 6) * 3) : (P2_FRAG + (ks - 6) * 3));
        gload(wsl + (size_t)(fid + wid) * 512,
              ring + ((t * 12 + ks + 6) & 7) * 1536 + wid * 512);
      }
      #pragma unroll
      for (int h = 0; h < 2; ++h) {
        bf16x8 av = (ks < 8) ? xa[h][ks] : ha[h][ks - 8];
        aR[h] = MFMA(av, b0, aR[h]);
        aZ[h] = MFMA(av, b1, aZ[h]);
        if (ks < 8) aNi[h] = MFMA(av, b2, aNi[h]);
        else        aNh[h] = MFMA(av, b2, aNh[h]);
      }
      if (wid < 3) WAIT_VM5;                   // oldest in-flight (step s+1) landed
      BAR;                                     // releases slot s+1; reads of s done
    }
    // elementwise GRU cell -> HsNew written in place into lT (bf16)
    int c = t * 16 + cl;
    #pragma unroll
    for (int h = 0; h < 2; ++h) {
      #pragma unroll
      for (int r = 0; r < 4; ++r) {
        int row = h * 16 + q * 4 + r;
        int bo = row * 256 + ((c * 2) ^ ((row & 7) << 4));
        float hsp = bf2f(*(const uint16_t*)((const char*)lT + bo));
        float rr = sigmoidf_(aR[h][r]);
        float zz = sigmoidf_(aZ[h][r]);
        float nn = tanhf_(aNi[h][r] + rr * aNh[h][r]);
        float hsn = (1.f - zz) * nn + zz * hsp;
        *(uint16_t*)((char*)lT + bo) = f2bf(hsn);
      }
    }
  }

  // ---- boundary: HsNew frags out of lT, then stage Hp into lT (wave-private) ----
  bf16x8 na[2][4];
  #pragma unroll
  for (int h = 0; h < 2; ++h) {
    int row = h * 16 + cl;
    #pragma unroll
    for (int ks = 0; ks < 4; ++ks) {
      int bo = row * 256 + (((ks * 64) + q * 16) ^ ((row & 7) << 4));
      na[h][ks] = *(const bf16x8*)((const char*)lT + bo);
    }
  }
  WAIT_LGKM0;                                  // na in regs before overwrite
  #pragma unroll
  for (int h = 0; h < 2; ++h) {
    int row = h * 16 + cl;
    #pragma unroll
    for (int ks = 0; ks < 4; ++ks) {
      int bo = row * 256 + (((ks * 64) + q * 16) ^ ((row & 7) << 4));
      *(bf16x8*)((char*)lT + bo) = pa[h][ks];
    }
  }

  // =========================== PASS 2 (task head) ===========================
  #pragma unroll 1
  for (int t = 0; t < 7; ++t) {
    f32x4 aZ[2], aR[2], aNa[2], aNb[2];
    #pragma unroll
    for (int h = 0; h < 2; ++h) { aZ[h] = (f32x4)(0.f); aR[h] = (f32x4)(0.f); aNa[h] = (f32x4)(0.f); aNb[h] = (f32x4)(0.f); }
    #pragma unroll
    for (int ks = 0; ks < 16; ++ks) {
      // consume slot s = 84 + t*16 + ks  -> slot (ks + 4 + 4t... ) use runtime calc
      const uint16_t* sp = ring + ((84 + t * 16 + ks) & 7) * 1536 + lane * 8;
      bf16x8 b0 = *(const bf16x8*)(sp);
      bf16x8 b1 = *(const bf16x8*)(sp + 512);
      bf16x8 b2 = *(const bf16x8*)(sp + 1024);
      if (wid < 3) {
        int fid = (ks < 10) ? (P2_FRAG + t * 48 + (ks + 6) * 3)
                : (t < 6 ? (P2_FRAG + (t + 1) * 48 + (ks - 10) * 3)
                         : (P2_FRAG + 6 * 48 + 15 * 3));   // tail clamp (redundant)
        gload(wsl + (size_t)(fid + wid) * 512,
              ring + ((84 + t * 16 + ks + 6) & 7) * 1536 + wid * 512);
      }
      #pragma unroll
      for (int h = 0; h < 2; ++h) {
        bf16x8 av = (ks < 8) ? xa[h][ks] : (ks < 12) ? pa[h][ks - 8] : na[h][ks - 12];
        aZ[h] = MFMA(av, b0, aZ[h]);
        aR[h] = MFMA(av, b1, aR[h]);
        if (ks < 8)       aNa[h] = MFMA(av, b2, aNa[h]);
        else if (ks < 12) aNb[h] = MFMA(av, b2, aNb[h]);
        else              aNa[h] = MFMA(av, b2, aNa[h]);
      }
      if (wid < 3) WAIT_VM5;
      BAR;
    }
    // elementwise + store (hpv from lT)
    int c = t * 16 + cl;
    bool valid = c < H_DIM;
    #pragma unroll
    for (int h = 0; h < 2; ++h) {
      #pragma unroll
      for (int r = 0; r < 4; ++r) {
        int row = h * 16 + q * 4 + r;
        int bo = row * 256 + ((c * 2) ^ ((row & 7) << 4));
        float hpv = bf2f(*(const uint16_t*)((const char*)lT + bo));
        float z2 = sigmoidf_(aZ[h][r]);
        float r2 = sigmoidf_(aR[h][r]);
        float nm = tanhf_(aNa[h][r] + r2 * aNb[h][r]);
        float hnew = (1.f - z2) * nm + z2 * hpv;
        if (valid) out[(size_t)(rowbase + row) * H_DIM + c] = hnew;
      }
    }
  }
}

extern "C" void kernel_launch(void* const* d_in, const int* in_sizes, int n_in,
                              void* d_out, int out_size, void* d_ws, size_t ws_size,
                              hipStream_t stream) {
  const float* x    = (const float*)d_in[0];
  const float* h_p  = (const float*)d_in[1];
  const float* h_s  = (const float*)d_in[2];
  const float* Wi   = (const float*)d_in[3];
  const float* Wh   = (const float*)d_in[4];
  const float* bi   = (const float*)d_in[5];
  const float* bh   = (const float*)d_in[6];
  const float* W_z  = (const float*)d_in[7];
  const float* U_z  = (const float*)d_in[8];
  const float* Us_z = (const float*)d_in[9];
  const float* W_r  = (const float*)d_in[10];
  const float* U_r  = (const float*)d_in[11];
  const float* Us_r = (const float*)d_in[12];
  const float* W_hn = (const float*)d_in[13];
  const float* U_hn = (const float*)d_in[14];
  const float* Us_hn= (const float*)d_in[15];
  uint16_t* ws = (uint16_t*)d_ws;
  float* out = (float*)d_out;

  int rows = in_sizes[0] / D_IN;          // 262144
  prepack_kernel<<<(TOTAL_E + 255) / 256, 256, 0, stream>>>(
      Wi, Wh, W_z, U_z, Us_z, W_r, U_r, Us_r, W_hn, U_hn, Us_hn, bi, bh, ws);
  gru_fused<<<rows / BM, NTHREADS, 0, stream>>>(x, h_p, h_s, ws, out);
}